// Round 10
// baseline (676.073 us; speedup 1.0000x reference)
//
#include <hip/hip_runtime.h>
#include <hip/hip_bf16.h>

// StyleGAN2 generator forward, MI355X round-10: r9 + barrier amortization.
// CPS (chunks-per-stage) template param: stage 64 ci (2x32 sub-chunks) per
// barrier pair, then two sequential tap-passes. Registers unchanged (afr/bfr
// reused per sub-pass; r6 regression was reg+LDS doubling). LDS: conv1 42 KB
// (3 blocks/CU), conv2/4/5 62 KB (2 blocks/CU) — r7 proved occupancy within
// 23-54% is not the lever; barrier count is (MfmaUtil 25->28.5->33.5 across
// r5->r8->r9 structural changes).
// Kept from r9: XCD pinning (z = blockIdx.x & 7), NR=2 s1 tiles, 32x32x16
// MFMA (C/D col=lane&31, row=(reg&3)+8*(reg>>2)+4*(lane>>5)), A-frag
// pre-swizzle, tap+1 A double-buffer.
//
// Workspace (bytes): 0 flag | 256 xA | 16640 xB | 33024 s_all | 51456 wmod
// (6,930,944 B) | 6,983,680 A1 arena 134 MB | 141,201,408 A2 arena 33.5 MB.
// Total 174,755,840 (proven available in round 4).

typedef __hip_bfloat16 bf16;
typedef __attribute__((ext_vector_type(8))) short bf16x8;
typedef __attribute__((ext_vector_type(16))) float f32x16;

__device__ __forceinline__ float b2f(bf16 v){ return __bfloat162float(v); }
__device__ __forceinline__ bf16  f2b(float v){ return __float2bfloat16(v); }
__device__ __forceinline__ unsigned short bbits(float v){
  bf16 h = f2b(v); union { bf16 h; unsigned short u; } x; x.h = h; return x.u;
}
__device__ __forceinline__ float ldf(const void* p, size_t i, int isf32){
  return isf32 ? ((const float*)p)[i] : b2f(((const bf16*)p)[i]);
}
__device__ __forceinline__ void stf(void* p, size_t i, int isf32, float v){
  if (isf32) ((float*)p)[i] = v; else ((bf16*)p)[i] = f2b(v);
}

// ---------------- dtype detector ----------------
__global__ __launch_bounds__(256) void detect_dtype(const unsigned short* __restrict__ cst,
    int* __restrict__ flag){
  __shared__ int cnt[256];
  int t = threadIdx.x, c = 0;
  for (int i=t; i<4096; i+=256){
    unsigned short w = cst[i];
    int mag = w & 0x7FFF;
    int e = mag >> 7;
    if (mag == 0 || (e >= 96 && e <= 150)) c++;
  }
  cnt[t] = c; __syncthreads();
  for (int s=128; s>0; s>>=1){ if (t<s) cnt[t] += cnt[t+s]; __syncthreads(); }
  if (t == 0) *flag = (cnt[0] >= 3500) ? 0 : 1;
}

// ---------------- const CHW -> NHWC bf16 ----------------
__global__ __launch_bounds__(256) void cvt_const(const void* __restrict__ cst,
    short* __restrict__ out, const int* __restrict__ dflag){
  int isf32 = *dflag;
  __shared__ __align__(16) short sh[64*136];
  int t = threadIdx.x;
  int p0 = blockIdx.x * 64;                         // 1024 blocks x 64 pixels
  for (int i=t; i<128*64; i+=256){
    int ci = i >> 6, px = i & 63;
    float v = ldf(cst, (size_t)ci*65536 + p0 + px, isf32);
    sh[px*136 + ci] = (short)bbits(v);
  }
  __syncthreads();
  for (int i=t; i<64*16; i+=256){
    int px = i >> 4, c8 = (i & 15) * 8;
    bf16x8 val = *(const bf16x8*)&sh[px*136 + c8];
    *(bf16x8*)(out + ((size_t)(p0+px))*128 + c8) = val;
  }
}

// ---------------- mapping network ----------------
__global__ __launch_bounds__(256) void map_init(const void* __restrict__ z,
    const int* __restrict__ labels, const void* __restrict__ emb,
    float* __restrict__ x0, const int* __restrict__ dflag){
  int isf32 = *dflag;
  int i = blockIdx.x*256 + threadIdx.x;
  int b = i >> 9, k = i & 511;
  x0[i] = ldf(z, i, isf32) + ldf(emb, (size_t)labels[b]*512 + k, isf32);
}

__global__ __launch_bounds__(64) void map_layer(const float* __restrict__ xin,
    float* __restrict__ xout, const void* __restrict__ W, size_t wOff,
    const void* __restrict__ bl, const void* __restrict__ gl,
    const void* __restrict__ betal, size_t vOff, const int* __restrict__ dflag){
  int isf32 = *dflag;
  int j = blockIdx.x;
  int l = threadIdx.x;
  int b = l >> 3, sp = l & 7;
  float part = 0.f;
  int k0 = sp*64;
  size_t wrow = wOff + (size_t)j*512 + k0;
  for (int k=0; k<64; k++)
    part += xin[b*512 + k0 + k] * ldf(W, wrow + k, isf32);
  part += __shfl_xor(part, 1);
  part += __shfl_xor(part, 2);
  part += __shfl_xor(part, 4);
  float y = part + ldf(bl, vOff + j, isf32);
  float ys[8];
  float mu = 0.f;
  #pragma unroll
  for (int bb=0; bb<8; bb++){ ys[bb] = __shfl(y, bb*8); mu += ys[bb]; }
  mu *= 0.125f;
  float var = 0.f;
  #pragma unroll
  for (int bb=0; bb<8; bb++){ float d = ys[bb]-mu; var += d*d; }
  var *= 0.125f;
  float xn = (y-mu)*rsqrtf(var+1e-5f)*ldf(gl, vOff + j, isf32) + ldf(betal, vOff + j, isf32);
  xn = (xn >= 0.f) ? xn : 0.2f*xn;
  if (sp == 0) xout[b*512 + j] = xn;
}

// ---------------- styles ----------------
__global__ __launch_bounds__(64) void styles_kernel(const float* __restrict__ w,
    float* __restrict__ s_all,
    const void* m0, const void* m1, const void* m2, const void* m3,
    const void* m4, const void* m5, const void* m6, const int* __restrict__ dflag){
  int isf32 = *dflag;
  int id = blockIdx.x;                            // 4608
  const int offs[8] = {0,1024,2048,3072,3584,4096,4352,4608};
  const int cins[7] = {128,128,128,64,64,32,32};
  const void* ms[7] = {m0,m1,m2,m3,m4,m5,m6};
  int c = 0;
  while (id >= offs[c+1]) c++;
  int r = id - offs[c];
  int Cin = cins[c];
  int b = r / Cin, ci = r % Cin;
  int l = threadIdx.x;
  float acc = 0.f;
  for (int k=l; k<512; k+=64) acc += w[b*512 + k] * ldf(ms[c], (size_t)ci*512 + k, isf32);
  #pragma unroll
  for (int m=1; m<64; m<<=1) acc += __shfl_xor(acc, m);
  if (l == 0) s_all[id] = acc;
}

// -------- modulate + demodulate + swizzle to 32x32x16 A-fragment order --------
// WA[b][tap][ci/32][co/32][kt][512], element (lane*8+j):
//   lane = ((ci>>3)&1)*32 + (co&31), kt = (ci>>4)&1, j = ci&7.
// rgb conv (1x1, no demod): plain [b][32].
__global__ __launch_bounds__(64) void modw_kernel(const float* __restrict__ s_all,
    bf16* __restrict__ wmod,
    const void* w0, const void* w1, const void* w2, const void* w3,
    const void* w4, const void* w5, const void* w6, const int* __restrict__ dflag){
  int isf32 = *dflag;
  int bid = blockIdx.x;
  int base, Cout, Cin, soff, wmoff, demod = 1;
  const void* wp;
  if      (bid < 1024){ base=0;    Cout=128; Cin=128; soff=0;    wmoff=0;       wp=w0; }
  else if (bid < 2048){ base=1024; Cout=128; Cin=128; soff=1024; wmoff=1179648; wp=w1; }
  else if (bid < 2560){ base=2048; Cout=64;  Cin=128; soff=2048; wmoff=2359296; wp=w2; }
  else if (bid < 3072){ base=2560; Cout=64;  Cin=64;  soff=3072; wmoff=2949120; wp=w3; }
  else if (bid < 3328){ base=3072; Cout=32;  Cin=64;  soff=3584; wmoff=3244032; wp=w4; }
  else if (bid < 3584){ base=3328; Cout=32;  Cin=32;  soff=4096; wmoff=3391488; wp=w5; }
  else                { base=3584; Cout=1;   Cin=32;  soff=4352; wmoff=3465216; wp=w6; demod=0; }
  int kk = demod ? 9 : 1;
  int L  = Cin * kk;
  int bc = bid - base;
  int b  = bc / Cout, co = bc % Cout;
  float scale = 1.0f / sqrtf((float)L);
  int l = threadIdx.x;
  float part = 0.f;
  for (int e=l; e<L; e+=64){
    int ci = e / kk;
    float v = scale * ldf(wp, (size_t)co*L + e, isf32) * s_all[soff + b*Cin + ci];
    part += v*v;
  }
  #pragma unroll
  for (int m=1; m<64; m<<=1) part += __shfl_xor(part, m);
  float d = demod ? rsqrtf(part + 1e-8f) : 1.0f;
  for (int e=l; e<L; e+=64){
    int ci = e / kk, tap = e % kk;
    float v = scale * ldf(wp, (size_t)co*L + e, isf32) * s_all[soff + b*Cin + ci];
    size_t idx;
    if (demod){
      int c32 = ci >> 5;
      int cog = co >> 5;
      int kt  = (ci >> 4) & 1;
      int lane2 = ((ci >> 3) & 1)*32 + (co & 31);
      int j = ci & 7;
      idx = (size_t)wmoff +
            ((((size_t)b*9 + tap)*(Cin>>5) + c32)*(Cout>>5) + cog)*1024 +
            kt*512 + lane2*8 + j;
    } else {
      idx = (size_t)wmoff + (size_t)b*Cin + e;
    }
    wmod[idx] = f2b(v * d);
  }
}

// -------- MFMA 32x32x16 implicit-GEMM 3x3 conv + noise + lrelu --------
// 1-D grid: z = blockIdx.x & 7 (XCD pin), tile = blockIdx.x >> 3.
// Block 256 = 4 waves MW x NW. Wave tile (MT2*32)co x (NT2*32)px.
// CPS sub-chunks of 32 ci staged per barrier pair; tap-pass per sub-chunk
// (registers reused across sub-passes -> no reg growth, only LDS).
template<int MT2, int NT2, int MW, int NW, int S, int WT, int NR, int CPS>
__global__ __launch_bounds__(256, 3) void convmf(
    const short* __restrict__ X, long long xbs, int Cin, int Hin, int Win,
    const bf16* __restrict__ WA, const void* __restrict__ noise,
    const void* __restrict__ nwp, short* __restrict__ Y, long long ybs,
    int Cout, int Hout, int Wout, const int* __restrict__ dflag){
  static_assert(MW*NW == 4, "4 waves");
  static_assert(NW*NT2*32 == WT*NR, "pixel tile");
  constexpr int W_in_t = (S==1) ? (WT+2) : (2*WT+1);
  constexpr int R_in   = (S==1) ? (NR+2) : (2*NR+1);
  constexpr int ENT    = R_in * W_in_t;
  __shared__ __align__(16) short act[CPS*ENT*40];
  int isf32 = *dflag;
  int t = threadIdx.x;
  int lane = t & 63, wv = t >> 6;
  int mw = wv % MW, nwv = wv / MW;
  int lane32 = lane & 31, half = lane >> 5;
  int z    = blockIdx.x & 7;                       // XCD pin
  int tile = blockIdx.x >> 3;
  int tiles_x = Wout / WT;
  int tx = tile % tiles_x, ty = tile / tiles_x;
  int ox0 = tx*WT, oy0 = ty*NR;
  int iy0 = S*oy0 - 1, ix0 = S*ox0 - 1;
  const short* Xb = X + (size_t)z * xbs;
  short* Yb = Y + (size_t)z * ybs;
  const int Cin32 = Cin >> 5, Cout32 = Cout >> 5;
  const bf16x8* WAimg = (const bf16x8*)WA + (size_t)z * 9 * Cin32 * Cout32 * 128;
  f32x16 acc[MT2][NT2];
  #pragma unroll
  for (int mt=0; mt<MT2; mt++)
    #pragma unroll
    for (int nt=0; nt<NT2; nt++)
      #pragma unroll
      for (int e=0; e<16; e++) acc[mt][nt][e] = 0.f;
  int rowb[NT2], xb[NT2];
  #pragma unroll
  for (int nt=0; nt<NT2; nt++){
    int nl = (nwv*NT2 + nt)*32;
    rowb[nt] = nl / WT;
    xb[nt]  = nl % WT + lane32;
  }
  bf16x8 afr[2][MT2][2];
  const int nouter = Cin32 / CPS;
  for (int oc=0; oc<nouter; oc++){
    __syncthreads();                               // WAR: prior reads done
    #pragma unroll
    for (int sub=0; sub<CPS; sub++){
      int c0 = (oc*CPS + sub) << 5;
      for (int i=t; i<ENT; i+=256){
        int r = i / W_in_t, x = i - r*W_in_t;
        int gy = iy0 + r, gx = ix0 + x;
        bf16x8* dst = (bf16x8*)&act[(size_t)(sub*ENT + i)*40];
        if (gy>=0 && gy<Hin && gx>=0 && gx<Win){
          const bf16x8* src = (const bf16x8*)(Xb + ((size_t)gy*Win + gx)*Cin + c0);
          dst[0]=src[0]; dst[1]=src[1]; dst[2]=src[2]; dst[3]=src[3];
        } else {
          bf16x8 zz = (bf16x8){0,0,0,0,0,0,0,0};
          dst[0]=zz; dst[1]=zz; dst[2]=zz; dst[3]=zz;
        }
      }
    }
    __syncthreads();
    #pragma unroll
    for (int sub=0; sub<CPS; sub++){
      int c32 = oc*CPS + sub;
      const bf16x8* WAc = WAimg + (size_t)c32 * Cout32 * 128;
      const int abase = sub*ENT;
      // preload tap 0 A-fragments
      #pragma unroll
      for (int mt=0; mt<MT2; mt++)
        #pragma unroll
        for (int kt=0; kt<2; kt++)
          afr[0][mt][kt] = WAc[((size_t)(mw*MT2+mt))*128 + kt*64 + lane];
      #pragma unroll
      for (int tap=0; tap<9; tap++){
        int cur = tap & 1, nxt = cur ^ 1;
        if (tap < 8){
          #pragma unroll
          for (int mt=0; mt<MT2; mt++)
            #pragma unroll
            for (int kt=0; kt<2; kt++)
              afr[nxt][mt][kt] = WAc[(size_t)(tap+1)*Cin32*Cout32*128 +
                                     ((size_t)(mw*MT2+mt))*128 + kt*64 + lane];
        }
        int ky = tap/3, kx = tap%3;
        bf16x8 bfr[NT2][2];
        #pragma unroll
        for (int nt=0; nt<NT2; nt++){
          int entry = abase + (S*rowb[nt] + ky)*W_in_t + (S*xb[nt] + kx);
          #pragma unroll
          for (int kt=0; kt<2; kt++)
            bfr[nt][kt] = *(const bf16x8*)&act[(size_t)entry*40 + kt*16 + half*8];
        }
        #pragma unroll
        for (int mt=0; mt<MT2; mt++)
          #pragma unroll
          for (int nt=0; nt<NT2; nt++)
            #pragma unroll
            for (int kt=0; kt<2; kt++)
              acc[mt][nt] = __builtin_amdgcn_mfma_f32_32x32x16_bf16(
                  afr[cur][mt][kt], bfr[nt][kt], acc[mt][nt], 0, 0, 0);
      }
    }
  }
  // epilogue: D col=lane&31 -> pixel, row=(reg&3)+8*(reg>>2)+4*half -> co.
  #pragma unroll
  for (int nt=0; nt<NT2; nt++){
    int oy = oy0 + rowb[nt], ox = ox0 + xb[nt];
    float nv = ldf(noise, ((size_t)z*Hout + oy)*Wout + ox, isf32);
    #pragma unroll
    for (int mt=0; mt<MT2; mt++){
      int cobase = (mw*MT2 + mt)*32 + half*4;
      #pragma unroll
      for (int g=0; g<4; g++){
        int co0 = cobase + 8*g;
        ushort4 pk;
        float v0 = acc[mt][nt][4*g+0] + ldf(nwp, co0+0, isf32)*nv; v0=(v0>=0.f)?v0:0.2f*v0;
        float v1 = acc[mt][nt][4*g+1] + ldf(nwp, co0+1, isf32)*nv; v1=(v1>=0.f)?v1:0.2f*v1;
        float v2 = acc[mt][nt][4*g+2] + ldf(nwp, co0+2, isf32)*nv; v2=(v2>=0.f)?v2:0.2f*v2;
        float v3 = acc[mt][nt][4*g+3] + ldf(nwp, co0+3, isf32)*nv; v3=(v3>=0.f)?v3:0.2f*v3;
        pk.x = bbits(v0); pk.y = bbits(v1); pk.z = bbits(v2); pk.w = bbits(v3);
        *(ushort4*)&Yb[((size_t)oy*Wout + ox)*Cout + co0] = pk;
      }
    }
  }
}

// ---------------- bilinear resize (NHWC 32x32x32 -> 256x240) + 1x1 to-gray ----
__global__ __launch_bounds__(256) void resize_rgb(const short* __restrict__ X,
    long long xbs, const bf16* __restrict__ wr, void* __restrict__ out,
    const int* __restrict__ dflag){
  int isf32 = *dflag;
  int b = blockIdx.y;
  const short* Xb = X + (size_t)b * xbs;
  int i = blockIdx.x*256 + threadIdx.x;           // 61440 per batch
  int x = i % 240;
  int y = i / 240;
  float sy = (y + 0.5f)*0.125f - 0.5f;
  float sx = (x + 0.5f)*(32.0f/240.0f) - 0.5f;
  float y0f = floorf(sy), x0f = floorf(sx);
  float fy = sy - y0f, fx = sx - x0f;
  int y0 = (int)y0f, x0 = (int)x0f;
  int y1 = min(y0+1, 31), x1 = min(x0+1, 31);
  y0 = max(y0, 0); x0 = max(x0, 0);
  const short* p00 = Xb + ((size_t)(y0*32 + x0))*32;
  const short* p01 = Xb + ((size_t)(y0*32 + x1))*32;
  const short* p10 = Xb + ((size_t)(y1*32 + x0))*32;
  const short* p11 = Xb + ((size_t)(y1*32 + x1))*32;
  float w00 = (1.f-fy)*(1.f-fx), w01 = (1.f-fy)*fx, w10 = fy*(1.f-fx), w11 = fy*fx;
  float acc = 0.f;
  for (int ci=0; ci<32; ci++){
    float v = w00*b2f(((const bf16*)p00)[ci]) + w01*b2f(((const bf16*)p01)[ci])
            + w10*b2f(((const bf16*)p10)[ci]) + w11*b2f(((const bf16*)p11)[ci]);
    acc += b2f(wr[b*32 + ci]) * v;
  }
  stf(out, (size_t)b*61440 + i, isf32, acc);
}

extern "C" void kernel_launch(void* const* d_in, const int* in_sizes, int n_in,
                              void* d_out, int out_size, void* d_ws, size_t ws_size,
                              hipStream_t stream){
  const void* z        = d_in[0];
  const int*  labels   = (const int*)d_in[1];
  const void* emb      = d_in[2];
  const void* map_W    = d_in[3];
  const void* map_b    = d_in[4];
  const void* map_g    = d_in[5];
  const void* map_beta = d_in[6];
  const void* cst      = d_in[7];
  const void* cw0 = d_in[8];   const void* cm0 = d_in[9];
  const void* cw1 = d_in[10];  const void* cm1 = d_in[11];
  const void* n1w = d_in[12];  const void* n2w = d_in[13];
  const void* cw2 = d_in[14];  const void* cm2 = d_in[15];
  const void* cw3 = d_in[16];  const void* cm3 = d_in[17];
  const void* n3w = d_in[18];  const void* n4w = d_in[19];
  const void* cw4 = d_in[20];  const void* cm4 = d_in[21];
  const void* cw5 = d_in[22];  const void* cm5 = d_in[23];
  const void* n5w = d_in[24];  const void* n6w = d_in[25];
  const void* cw6 = d_in[26];  const void* cm6 = d_in[27];
  const void* n1a = d_in[28];  const void* n1b = d_in[29];
  const void* n2a = d_in[30];  const void* n2b = d_in[31];
  const void* n3a = d_in[32];  const void* n3b = d_in[33];

  int*   flag  = (int*)d_ws;
  float* xA    = (float*)((char*)d_ws + 256);
  float* xB    = (float*)((char*)d_ws + 16640);
  float* s_all = (float*)((char*)d_ws + 33024);
  bf16*  wmod  = (bf16*)((char*)d_ws + 51456);
  short* A1    = (short*)((char*)d_ws + 6983680);    // 134,217,728 B
  short* A2    = (short*)((char*)d_ws + 141201408);  //  33,554,432 B

  detect_dtype<<<1,256,0,stream>>>((const unsigned short*)cst, flag);
  cvt_const<<<1024,256,0,stream>>>(cst, A2, flag);   // cstT in A2 (dead after conv1)
  map_init<<<16,256,0,stream>>>(z, labels, emb, xA, flag);
  float* cur = xA; float* nxt = xB;
  for (int l=0; l<8; l++){
    map_layer<<<512,64,0,stream>>>(cur, nxt, map_W, (size_t)l*512*512,
                                   map_b, map_g, map_beta, (size_t)l*512, flag);
    float* tmp = cur; cur = nxt; nxt = tmp;
  }
  styles_kernel<<<4608,64,0,stream>>>(cur, s_all, cm0, cm1, cm2, cm3, cm4, cm5, cm6, flag);
  modw_kernel<<<3592,64,0,stream>>>(s_all, wmod, cw0, cw1, cw2, cw3, cw4, cw5, cw6, flag);

  bf16* wm0 = wmod;
  bf16* wm1 = wmod + 1179648;
  bf16* wm2 = wmod + 2359296;
  bf16* wm3 = wmod + 2949120;
  bf16* wm4 = wmod + 3244032;
  bf16* wm5 = wmod + 3391488;
  bf16* wm6 = wmod + 3465216;

  const long long A1e  = 256LL*256*128;  // a1  NHWC elems/img
  const long long A1Be = 128LL*128*128;  // a1b
  const long long A2e  = 128LL*128*64;   // a2
  const long long A2Be = 64LL*64*64;     // a2b
  const long long A3e  = 64LL*64*32;     // a3
  const long long A3Be = 32LL*32*32;     // a3b

  // conv1: cstT(A2) -> a1(A1).  128co x 128px (64x2), s1, CPS=2 (LDS 42 KB).
  convmf<2,2,2,2,1,64,2,2><<<4096,256,0,stream>>>(A2, 0, 128, 256, 256,
      wm0, n1a, n1w, A1, A1e, 128, 256, 256, flag);
  // conv2: a1(A1) -> a1b(A2).  128co x 64px (64x1), s2, CPS=2 (LDS 62 KB).
  convmf<2,1,2,2,2,64,1,2><<<2048,256,0,stream>>>(A1, A1e, 128, 256, 256,
      wm1, n1b, n2w, A2, A1Be, 128, 128, 128, flag);
  // conv3: a1b(A2) -> a2(A1).  64co x 128px (64x2), s1, CPS=2 (LDS 42 KB).
  convmf<1,2,2,2,1,64,2,2><<<1024,256,0,stream>>>(A2, A1Be, 128, 128, 128,
      wm2, n2a, n3w, A1, A2e, 64, 128, 128, flag);
  // conv4: a2(A1) -> a2b(A2).  64co x 64px (64x1), s2, CPS=2 (LDS 62 KB, 1 stage).
  convmf<1,1,2,2,2,64,1,2><<<512,256,0,stream>>>(A1, A2e, 64, 128, 128,
      wm3, n2b, n4w, A2, A2Be, 64, 64, 64, flag);
  // conv5: a2b(A2) -> a3(A1).  32co x 256px (64x4), s1, CPS=2 (LDS 63 KB, 1 stage).
  convmf<1,2,1,4,1,64,4,2><<<128,256,0,stream>>>(A2, A2Be, 64, 64, 64,
      wm4, n3a, n5w, A1, A3e, 32, 64, 64, flag);
  // conv6: a3(A1) -> a3b(A2).  32co x 128px (32x4), s2, CPS=1 (Cin32=1).
  convmf<1,1,1,4,2,32,4,1><<<64,256,0,stream>>>(A1, A3e, 32, 64, 64,
      wm5, n3b, n6w, A2, A3Be, 32, 32, 32, flag);
  // resize + to-gray -> d_out
  resize_rgb<<<dim3(240,8),256,0,stream>>>(A2, A3Be, wm6, d_out, flag);
}

// Round 11
// 622.106 us; speedup vs baseline: 1.0867x; 1.0867x over previous
//
#include <hip/hip_runtime.h>
#include <hip/hip_bf16.h>

// StyleGAN2 generator forward, MI355X round-11: revert to r9 shapes (CPS=1;
// r10's CPS=2 regressed: barrier amortization paid in occupancy, m132-style),
// except conv1 re-tiled to 64co x 128px wave tiles (MT2=2,NT2=4, block
// 128co x 256px): 16 MFMA (128 matrix-cyc) per 4 A-fragment L2 loads per tap
// -> 2x arithmetic per loaded fragment, A-load count halved; 2 waves/SIMD
// suffice to hide ~200cyc L2 latency (2x128=256cyc). launch_bounds waves is
// a template param: conv1 (256,2) for ~220 VGPR, others (256,3) as r9.
// History: r8 2xK MFMA +, r9 XCD pin + NR2 +, r6/r10 barrier attacks -,
// r7 occupancy alone neutral. SQ_LDS_BANK_CONFLICT@16x16 was an artifact.
//
// Workspace (bytes): 0 flag | 256 xA | 16640 xB | 33024 s_all | 51456 wmod
// (6,930,944 B) | 6,983,680 A1 arena 134 MB | 141,201,408 A2 arena 33.5 MB.
// Total 174,755,840 (proven available in round 4).

typedef __hip_bfloat16 bf16;
typedef __attribute__((ext_vector_type(8))) short bf16x8;
typedef __attribute__((ext_vector_type(16))) float f32x16;

__device__ __forceinline__ float b2f(bf16 v){ return __bfloat162float(v); }
__device__ __forceinline__ bf16  f2b(float v){ return __float2bfloat16(v); }
__device__ __forceinline__ unsigned short bbits(float v){
  bf16 h = f2b(v); union { bf16 h; unsigned short u; } x; x.h = h; return x.u;
}
__device__ __forceinline__ float ldf(const void* p, size_t i, int isf32){
  return isf32 ? ((const float*)p)[i] : b2f(((const bf16*)p)[i]);
}
__device__ __forceinline__ void stf(void* p, size_t i, int isf32, float v){
  if (isf32) ((float*)p)[i] = v; else ((bf16*)p)[i] = f2b(v);
}

// ---------------- dtype detector ----------------
__global__ __launch_bounds__(256) void detect_dtype(const unsigned short* __restrict__ cst,
    int* __restrict__ flag){
  __shared__ int cnt[256];
  int t = threadIdx.x, c = 0;
  for (int i=t; i<4096; i+=256){
    unsigned short w = cst[i];
    int mag = w & 0x7FFF;
    int e = mag >> 7;
    if (mag == 0 || (e >= 96 && e <= 150)) c++;
  }
  cnt[t] = c; __syncthreads();
  for (int s=128; s>0; s>>=1){ if (t<s) cnt[t] += cnt[t+s]; __syncthreads(); }
  if (t == 0) *flag = (cnt[0] >= 3500) ? 0 : 1;
}

// ---------------- const CHW -> NHWC bf16 ----------------
__global__ __launch_bounds__(256) void cvt_const(const void* __restrict__ cst,
    short* __restrict__ out, const int* __restrict__ dflag){
  int isf32 = *dflag;
  __shared__ __align__(16) short sh[64*136];
  int t = threadIdx.x;
  int p0 = blockIdx.x * 64;                         // 1024 blocks x 64 pixels
  for (int i=t; i<128*64; i+=256){
    int ci = i >> 6, px = i & 63;
    float v = ldf(cst, (size_t)ci*65536 + p0 + px, isf32);
    sh[px*136 + ci] = (short)bbits(v);
  }
  __syncthreads();
  for (int i=t; i<64*16; i+=256){
    int px = i >> 4, c8 = (i & 15) * 8;
    bf16x8 val = *(const bf16x8*)&sh[px*136 + c8];
    *(bf16x8*)(out + ((size_t)(p0+px))*128 + c8) = val;
  }
}

// ---------------- mapping network ----------------
__global__ __launch_bounds__(256) void map_init(const void* __restrict__ z,
    const int* __restrict__ labels, const void* __restrict__ emb,
    float* __restrict__ x0, const int* __restrict__ dflag){
  int isf32 = *dflag;
  int i = blockIdx.x*256 + threadIdx.x;
  int b = i >> 9, k = i & 511;
  x0[i] = ldf(z, i, isf32) + ldf(emb, (size_t)labels[b]*512 + k, isf32);
}

__global__ __launch_bounds__(64) void map_layer(const float* __restrict__ xin,
    float* __restrict__ xout, const void* __restrict__ W, size_t wOff,
    const void* __restrict__ bl, const void* __restrict__ gl,
    const void* __restrict__ betal, size_t vOff, const int* __restrict__ dflag){
  int isf32 = *dflag;
  int j = blockIdx.x;
  int l = threadIdx.x;
  int b = l >> 3, sp = l & 7;
  float part = 0.f;
  int k0 = sp*64;
  size_t wrow = wOff + (size_t)j*512 + k0;
  for (int k=0; k<64; k++)
    part += xin[b*512 + k0 + k] * ldf(W, wrow + k, isf32);
  part += __shfl_xor(part, 1);
  part += __shfl_xor(part, 2);
  part += __shfl_xor(part, 4);
  float y = part + ldf(bl, vOff + j, isf32);
  float ys[8];
  float mu = 0.f;
  #pragma unroll
  for (int bb=0; bb<8; bb++){ ys[bb] = __shfl(y, bb*8); mu += ys[bb]; }
  mu *= 0.125f;
  float var = 0.f;
  #pragma unroll
  for (int bb=0; bb<8; bb++){ float d = ys[bb]-mu; var += d*d; }
  var *= 0.125f;
  float xn = (y-mu)*rsqrtf(var+1e-5f)*ldf(gl, vOff + j, isf32) + ldf(betal, vOff + j, isf32);
  xn = (xn >= 0.f) ? xn : 0.2f*xn;
  if (sp == 0) xout[b*512 + j] = xn;
}

// ---------------- styles ----------------
__global__ __launch_bounds__(64) void styles_kernel(const float* __restrict__ w,
    float* __restrict__ s_all,
    const void* m0, const void* m1, const void* m2, const void* m3,
    const void* m4, const void* m5, const void* m6, const int* __restrict__ dflag){
  int isf32 = *dflag;
  int id = blockIdx.x;                            // 4608
  const int offs[8] = {0,1024,2048,3072,3584,4096,4352,4608};
  const int cins[7] = {128,128,128,64,64,32,32};
  const void* ms[7] = {m0,m1,m2,m3,m4,m5,m6};
  int c = 0;
  while (id >= offs[c+1]) c++;
  int r = id - offs[c];
  int Cin = cins[c];
  int b = r / Cin, ci = r % Cin;
  int l = threadIdx.x;
  float acc = 0.f;
  for (int k=l; k<512; k+=64) acc += w[b*512 + k] * ldf(ms[c], (size_t)ci*512 + k, isf32);
  #pragma unroll
  for (int m=1; m<64; m<<=1) acc += __shfl_xor(acc, m);
  if (l == 0) s_all[id] = acc;
}

// -------- modulate + demodulate + swizzle to 32x32x16 A-fragment order --------
// WA[b][tap][ci/32][co/32][kt][512], element (lane*8+j):
//   lane = ((ci>>3)&1)*32 + (co&31), kt = (ci>>4)&1, j = ci&7.
// rgb conv (1x1, no demod): plain [b][32].
__global__ __launch_bounds__(64) void modw_kernel(const float* __restrict__ s_all,
    bf16* __restrict__ wmod,
    const void* w0, const void* w1, const void* w2, const void* w3,
    const void* w4, const void* w5, const void* w6, const int* __restrict__ dflag){
  int isf32 = *dflag;
  int bid = blockIdx.x;
  int base, Cout, Cin, soff, wmoff, demod = 1;
  const void* wp;
  if      (bid < 1024){ base=0;    Cout=128; Cin=128; soff=0;    wmoff=0;       wp=w0; }
  else if (bid < 2048){ base=1024; Cout=128; Cin=128; soff=1024; wmoff=1179648; wp=w1; }
  else if (bid < 2560){ base=2048; Cout=64;  Cin=128; soff=2048; wmoff=2359296; wp=w2; }
  else if (bid < 3072){ base=2560; Cout=64;  Cin=64;  soff=3072; wmoff=2949120; wp=w3; }
  else if (bid < 3328){ base=3072; Cout=32;  Cin=64;  soff=3584; wmoff=3244032; wp=w4; }
  else if (bid < 3584){ base=3328; Cout=32;  Cin=32;  soff=4096; wmoff=3391488; wp=w5; }
  else                { base=3584; Cout=1;   Cin=32;  soff=4352; wmoff=3465216; wp=w6; demod=0; }
  int kk = demod ? 9 : 1;
  int L  = Cin * kk;
  int bc = bid - base;
  int b  = bc / Cout, co = bc % Cout;
  float scale = 1.0f / sqrtf((float)L);
  int l = threadIdx.x;
  float part = 0.f;
  for (int e=l; e<L; e+=64){
    int ci = e / kk;
    float v = scale * ldf(wp, (size_t)co*L + e, isf32) * s_all[soff + b*Cin + ci];
    part += v*v;
  }
  #pragma unroll
  for (int m=1; m<64; m<<=1) part += __shfl_xor(part, m);
  float d = demod ? rsqrtf(part + 1e-8f) : 1.0f;
  for (int e=l; e<L; e+=64){
    int ci = e / kk, tap = e % kk;
    float v = scale * ldf(wp, (size_t)co*L + e, isf32) * s_all[soff + b*Cin + ci];
    size_t idx;
    if (demod){
      int c32 = ci >> 5;
      int cog = co >> 5;
      int kt  = (ci >> 4) & 1;
      int lane2 = ((ci >> 3) & 1)*32 + (co & 31);
      int j = ci & 7;
      idx = (size_t)wmoff +
            ((((size_t)b*9 + tap)*(Cin>>5) + c32)*(Cout>>5) + cog)*1024 +
            kt*512 + lane2*8 + j;
    } else {
      idx = (size_t)wmoff + (size_t)b*Cin + e;
    }
    wmod[idx] = f2b(v * d);
  }
}

// -------- MFMA 32x32x16 implicit-GEMM 3x3 conv + noise + lrelu --------
// 1-D grid: z = blockIdx.x & 7 (XCD pin), tile = blockIdx.x >> 3.
// Block 256 = 4 waves MW x NW. Wave tile (MT2*32)co x (NT2*32)px.
// WAVES = __launch_bounds__ min-waves/SIMD (2 for the big conv1 tile).
template<int MT2, int NT2, int MW, int NW, int S, int WT, int NR, int WAVES>
__global__ __launch_bounds__(256, WAVES) void convmf(
    const short* __restrict__ X, long long xbs, int Cin, int Hin, int Win,
    const bf16* __restrict__ WA, const void* __restrict__ noise,
    const void* __restrict__ nwp, short* __restrict__ Y, long long ybs,
    int Cout, int Hout, int Wout, const int* __restrict__ dflag){
  static_assert(MW*NW == 4, "4 waves");
  static_assert(NW*NT2*32 == WT*NR, "pixel tile");
  constexpr int W_in_t = (S==1) ? (WT+2) : (2*WT+1);
  constexpr int R_in   = (S==1) ? (NR+2) : (2*NR+1);
  constexpr int ENT    = R_in * W_in_t;
  __shared__ __align__(16) short act[ENT*40];
  int isf32 = *dflag;
  int t = threadIdx.x;
  int lane = t & 63, wv = t >> 6;
  int mw = wv % MW, nwv = wv / MW;
  int lane32 = lane & 31, half = lane >> 5;
  int z    = blockIdx.x & 7;                       // XCD pin
  int tile = blockIdx.x >> 3;
  int tiles_x = Wout / WT;
  int tx = tile % tiles_x, ty = tile / tiles_x;
  int ox0 = tx*WT, oy0 = ty*NR;
  int iy0 = S*oy0 - 1, ix0 = S*ox0 - 1;
  const short* Xb = X + (size_t)z * xbs;
  short* Yb = Y + (size_t)z * ybs;
  const int Cin32 = Cin >> 5, Cout32 = Cout >> 5;
  const bf16x8* WAimg = (const bf16x8*)WA + (size_t)z * 9 * Cin32 * Cout32 * 128;
  f32x16 acc[MT2][NT2];
  #pragma unroll
  for (int mt=0; mt<MT2; mt++)
    #pragma unroll
    for (int nt=0; nt<NT2; nt++)
      #pragma unroll
      for (int e=0; e<16; e++) acc[mt][nt][e] = 0.f;
  int rowb[NT2], xb[NT2];
  #pragma unroll
  for (int nt=0; nt<NT2; nt++){
    int nl = (nwv*NT2 + nt)*32;
    rowb[nt] = nl / WT;
    xb[nt]  = nl % WT + lane32;
  }
  bf16x8 afr[2][MT2][2];
  for (int c32=0; c32<Cin32; c32++){
    int c0 = c32 << 5;
    __syncthreads();                               // WAR: prior reads done
    for (int i=t; i<ENT; i+=256){
      int r = i / W_in_t, x = i - r*W_in_t;
      int gy = iy0 + r, gx = ix0 + x;
      bf16x8* dst = (bf16x8*)&act[i*40];
      if (gy>=0 && gy<Hin && gx>=0 && gx<Win){
        const bf16x8* src = (const bf16x8*)(Xb + ((size_t)gy*Win + gx)*Cin + c0);
        dst[0]=src[0]; dst[1]=src[1]; dst[2]=src[2]; dst[3]=src[3];
      } else {
        bf16x8 zz = (bf16x8){0,0,0,0,0,0,0,0};
        dst[0]=zz; dst[1]=zz; dst[2]=zz; dst[3]=zz;
      }
    }
    __syncthreads();
    const bf16x8* WAc = WAimg + (size_t)c32 * Cout32 * 128;
    // preload tap 0 A-fragments
    #pragma unroll
    for (int mt=0; mt<MT2; mt++)
      #pragma unroll
      for (int kt=0; kt<2; kt++)
        afr[0][mt][kt] = WAc[((size_t)(mw*MT2+mt))*128 + kt*64 + lane];
    #pragma unroll
    for (int tap=0; tap<9; tap++){
      int cur = tap & 1, nxt = cur ^ 1;
      if (tap < 8){
        #pragma unroll
        for (int mt=0; mt<MT2; mt++)
          #pragma unroll
          for (int kt=0; kt<2; kt++)
            afr[nxt][mt][kt] = WAc[(size_t)(tap+1)*Cin32*Cout32*128 +
                                   ((size_t)(mw*MT2+mt))*128 + kt*64 + lane];
      }
      int ky = tap/3, kx = tap%3;
      bf16x8 bfr[NT2][2];
      #pragma unroll
      for (int nt=0; nt<NT2; nt++){
        int entry = (S*rowb[nt] + ky)*W_in_t + (S*xb[nt] + kx);
        #pragma unroll
        for (int kt=0; kt<2; kt++)
          bfr[nt][kt] = *(const bf16x8*)&act[(size_t)entry*40 + kt*16 + half*8];
      }
      #pragma unroll
      for (int mt=0; mt<MT2; mt++)
        #pragma unroll
        for (int nt=0; nt<NT2; nt++)
          #pragma unroll
          for (int kt=0; kt<2; kt++)
            acc[mt][nt] = __builtin_amdgcn_mfma_f32_32x32x16_bf16(
                afr[cur][mt][kt], bfr[nt][kt], acc[mt][nt], 0, 0, 0);
    }
  }
  // epilogue: D col=lane&31 -> pixel, row=(reg&3)+8*(reg>>2)+4*half -> co.
  #pragma unroll
  for (int nt=0; nt<NT2; nt++){
    int oy = oy0 + rowb[nt], ox = ox0 + xb[nt];
    float nv = ldf(noise, ((size_t)z*Hout + oy)*Wout + ox, isf32);
    #pragma unroll
    for (int mt=0; mt<MT2; mt++){
      int cobase = (mw*MT2 + mt)*32 + half*4;
      #pragma unroll
      for (int g=0; g<4; g++){
        int co0 = cobase + 8*g;
        ushort4 pk;
        float v0 = acc[mt][nt][4*g+0] + ldf(nwp, co0+0, isf32)*nv; v0=(v0>=0.f)?v0:0.2f*v0;
        float v1 = acc[mt][nt][4*g+1] + ldf(nwp, co0+1, isf32)*nv; v1=(v1>=0.f)?v1:0.2f*v1;
        float v2 = acc[mt][nt][4*g+2] + ldf(nwp, co0+2, isf32)*nv; v2=(v2>=0.f)?v2:0.2f*v2;
        float v3 = acc[mt][nt][4*g+3] + ldf(nwp, co0+3, isf32)*nv; v3=(v3>=0.f)?v3:0.2f*v3;
        pk.x = bbits(v0); pk.y = bbits(v1); pk.z = bbits(v2); pk.w = bbits(v3);
        *(ushort4*)&Yb[((size_t)oy*Wout + ox)*Cout + co0] = pk;
      }
    }
  }
}

// ---------------- bilinear resize (NHWC 32x32x32 -> 256x240) + 1x1 to-gray ----
__global__ __launch_bounds__(256) void resize_rgb(const short* __restrict__ X,
    long long xbs, const bf16* __restrict__ wr, void* __restrict__ out,
    const int* __restrict__ dflag){
  int isf32 = *dflag;
  int b = blockIdx.y;
  const short* Xb = X + (size_t)b * xbs;
  int i = blockIdx.x*256 + threadIdx.x;           // 61440 per batch
  int x = i % 240;
  int y = i / 240;
  float sy = (y + 0.5f)*0.125f - 0.5f;
  float sx = (x + 0.5f)*(32.0f/240.0f) - 0.5f;
  float y0f = floorf(sy), x0f = floorf(sx);
  float fy = sy - y0f, fx = sx - x0f;
  int y0 = (int)y0f, x0 = (int)x0f;
  int y1 = min(y0+1, 31), x1 = min(x0+1, 31);
  y0 = max(y0, 0); x0 = max(x0, 0);
  const short* p00 = Xb + ((size_t)(y0*32 + x0))*32;
  const short* p01 = Xb + ((size_t)(y0*32 + x1))*32;
  const short* p10 = Xb + ((size_t)(y1*32 + x0))*32;
  const short* p11 = Xb + ((size_t)(y1*32 + x1))*32;
  float w00 = (1.f-fy)*(1.f-fx), w01 = (1.f-fy)*fx, w10 = fy*(1.f-fx), w11 = fy*fx;
  float acc = 0.f;
  for (int ci=0; ci<32; ci++){
    float v = w00*b2f(((const bf16*)p00)[ci]) + w01*b2f(((const bf16*)p01)[ci])
            + w10*b2f(((const bf16*)p10)[ci]) + w11*b2f(((const bf16*)p11)[ci]);
    acc += b2f(wr[b*32 + ci]) * v;
  }
  stf(out, (size_t)b*61440 + i, isf32, acc);
}

extern "C" void kernel_launch(void* const* d_in, const int* in_sizes, int n_in,
                              void* d_out, int out_size, void* d_ws, size_t ws_size,
                              hipStream_t stream){
  const void* z        = d_in[0];
  const int*  labels   = (const int*)d_in[1];
  const void* emb      = d_in[2];
  const void* map_W    = d_in[3];
  const void* map_b    = d_in[4];
  const void* map_g    = d_in[5];
  const void* map_beta = d_in[6];
  const void* cst      = d_in[7];
  const void* cw0 = d_in[8];   const void* cm0 = d_in[9];
  const void* cw1 = d_in[10];  const void* cm1 = d_in[11];
  const void* n1w = d_in[12];  const void* n2w = d_in[13];
  const void* cw2 = d_in[14];  const void* cm2 = d_in[15];
  const void* cw3 = d_in[16];  const void* cm3 = d_in[17];
  const void* n3w = d_in[18];  const void* n4w = d_in[19];
  const void* cw4 = d_in[20];  const void* cm4 = d_in[21];
  const void* cw5 = d_in[22];  const void* cm5 = d_in[23];
  const void* n5w = d_in[24];  const void* n6w = d_in[25];
  const void* cw6 = d_in[26];  const void* cm6 = d_in[27];
  const void* n1a = d_in[28];  const void* n1b = d_in[29];
  const void* n2a = d_in[30];  const void* n2b = d_in[31];
  const void* n3a = d_in[32];  const void* n3b = d_in[33];

  int*   flag  = (int*)d_ws;
  float* xA    = (float*)((char*)d_ws + 256);
  float* xB    = (float*)((char*)d_ws + 16640);
  float* s_all = (float*)((char*)d_ws + 33024);
  bf16*  wmod  = (bf16*)((char*)d_ws + 51456);
  short* A1    = (short*)((char*)d_ws + 6983680);    // 134,217,728 B
  short* A2    = (short*)((char*)d_ws + 141201408);  //  33,554,432 B

  detect_dtype<<<1,256,0,stream>>>((const unsigned short*)cst, flag);
  cvt_const<<<1024,256,0,stream>>>(cst, A2, flag);   // cstT in A2 (dead after conv1)
  map_init<<<16,256,0,stream>>>(z, labels, emb, xA, flag);
  float* cur = xA; float* nxt = xB;
  for (int l=0; l<8; l++){
    map_layer<<<512,64,0,stream>>>(cur, nxt, map_W, (size_t)l*512*512,
                                   map_b, map_g, map_beta, (size_t)l*512, flag);
    float* tmp = cur; cur = nxt; nxt = tmp;
  }
  styles_kernel<<<4608,64,0,stream>>>(cur, s_all, cm0, cm1, cm2, cm3, cm4, cm5, cm6, flag);
  modw_kernel<<<3592,64,0,stream>>>(s_all, wmod, cw0, cw1, cw2, cw3, cw4, cw5, cw6, flag);

  bf16* wm0 = wmod;
  bf16* wm1 = wmod + 1179648;
  bf16* wm2 = wmod + 2359296;
  bf16* wm3 = wmod + 2949120;
  bf16* wm4 = wmod + 3244032;
  bf16* wm5 = wmod + 3391488;
  bf16* wm6 = wmod + 3465216;

  const long long A1e  = 256LL*256*128;  // a1  NHWC elems/img
  const long long A1Be = 128LL*128*128;  // a1b
  const long long A2e  = 128LL*128*64;   // a2
  const long long A2Be = 64LL*64*64;     // a2b
  const long long A3e  = 64LL*64*32;     // a3
  const long long A3Be = 32LL*32*32;     // a3b

  // conv1: cstT(A2) -> a1(A1).  BIG TILE: 128co x 256px (64x4 rows), s1,
  // waves 64co x 128px (MT2=2,NT2=4), launch_bounds(256,2). 256 tiles/img.
  convmf<2,4,2,2,1,64,4,2><<<2048,256,0,stream>>>(A2, 0, 128, 256, 256,
      wm0, n1a, n1w, A1, A1e, 128, 256, 256, flag);
  // conv2: a1(A1) -> a1b(A2).  128co x 64px (64x1), s2. 256 tiles/img. (r9)
  convmf<2,1,2,2,2,64,1,3><<<2048,256,0,stream>>>(A1, A1e, 128, 256, 256,
      wm1, n1b, n2w, A2, A1Be, 128, 128, 128, flag);
  // conv3: a1b(A2) -> a2(A1).  64co x 128px (64x2), s1. 128 tiles/img. (r9)
  convmf<1,2,2,2,1,64,2,3><<<1024,256,0,stream>>>(A2, A1Be, 128, 128, 128,
      wm2, n2a, n3w, A1, A2e, 64, 128, 128, flag);
  // conv4: a2(A1) -> a2b(A2).  64co x 64px (64x1), s2. 64 tiles/img. (r9)
  convmf<1,1,2,2,2,64,1,3><<<512,256,0,stream>>>(A1, A2e, 64, 128, 128,
      wm3, n2b, n4w, A2, A2Be, 64, 64, 64, flag);
  // conv5: a2b(A2) -> a3(A1).  32co x 256px (64x4), s1. 16 tiles/img. (r9)
  convmf<1,2,1,4,1,64,4,3><<<128,256,0,stream>>>(A2, A2Be, 64, 64, 64,
      wm4, n3a, n5w, A1, A3e, 32, 64, 64, flag);
  // conv6: a3(A1) -> a3b(A2).  32co x 128px (32x4), s2. 8 tiles/img. (r9)
  convmf<1,1,1,4,2,32,4,3><<<64,256,0,stream>>>(A1, A3e, 32, 64, 64,
      wm5, n3b, n6w, A2, A3Be, 32, 32, 32, flag);
  // resize + to-gray -> d_out
  resize_rgb<<<dim3(240,8),256,0,stream>>>(A2, A3Be, wm6, d_out, flag);
}